// Round 2
// baseline (223.456 us; speedup 1.0000x reference)
//
#include <hip/hip_runtime.h>

// RoDAlignMax: features [4,256,64,64] f32, rois [2048,5] -> out [2048,256,9,9] f32
// Grid samples are exactly (7i, 7j): bilinear degenerates to a gather.
// Kernel 1: gather G[b][p][c] (p = i*10+j, 100 points) = F[b,c,7i,7j]  (400 KB, L2-resident)
// Kernel 2: one wave per (roi, channel-quarter), lane = channel. Masked 10x10 ->
//           2x2/s1 maxpool -> 9x9, stored DIRECTLY per lane (channel's 81 outputs are
//           contiguous in global). No LDS at all -> ~24 waves/CU instead of 7:
//           L2 load latency and store issue hide under other waves.

#define NB 4
#define NC 256
#define HW 64
#define NR 2048

typedef float f4v __attribute__((ext_vector_type(4), aligned(4)));

__global__ __launch_bounds__(256) void rod_gather(const float* __restrict__ F,
                                                  float* __restrict__ G) {
    int idx = blockIdx.x * 256 + threadIdx.x;      // < 4*100*256 = 102400
    int c = idx & 255;
    int t = idx >> 8;                              // b*100 + p
    int p = t % 100;
    int b = t / 100;
    int i = p / 10, j = p - i * 10;
    // F[((b*256 + c)*64 + 7i)*64 + 7j]
    G[idx] = F[((b * NC + c) << 12) + i * 448 + j * 7];
}

__global__ __launch_bounds__(64, 6) void rod_main(const float* __restrict__ G,
                                                  const float* __restrict__ rois,
                                                  float* __restrict__ out) {
    const int tid = threadIdx.x;
    const int r   = blockIdx.x >> 2;
    const int q   = blockIdx.x & 3;                // channel quarter
    const int c   = (q << 6) + tid;

    const float x1 = rois[r * 5 + 1] * 0.25f;
    const float y1 = rois[r * 5 + 2] * 0.25f;
    const float x2 = rois[r * 5 + 3] * 0.25f;
    const float y2 = rois[r * 5 + 4] * 0.25f;
    const int  b   = (int)rois[r * 5 + 0];

    bool inw[10], inh[10];                         // wave-uniform (scalar) masks
    #pragma unroll
    for (int j = 0; j < 10; ++j) {
        float s = 7.0f * (float)j;                 // exact grid coordinate
        inw[j] = (s >= x1) && (s <= x2);
        inh[j] = (s >= y1) && (s <= y2);
    }

    // G[b][p][c]: stride 256 floats per p; lanes (consecutive c) coalesce each load.
    const float* gb = G + (size_t)b * 100 * NC + c;
    // Lane's 81 outputs are contiguous: out[r][c][0..80].
    float* dst = out + (size_t)r * 20736 + (size_t)c * 81;

    float raw1[10];                                // row i raw values (in flight)
    float vprev[10];
    {
        float raw0[10];
        #pragma unroll
        for (int j = 0; j < 10; ++j) raw0[j] = gb[j * NC];          // row 0
        #pragma unroll
        for (int j = 0; j < 10; ++j) raw1[j] = gb[(10 + j) * NC];   // prefetch row 1
        #pragma unroll
        for (int j = 0; j < 10; ++j) vprev[j] = (inh[0] && inw[j]) ? 0.0f : raw0[j];
    }

    #pragma unroll
    for (int i = 1; i < 10; ++i) {
        float rawn[10];
        if (i < 9) {                               // prefetch row i+1 before consuming row i
            #pragma unroll
            for (int j = 0; j < 10; ++j) rawn[j] = gb[((i + 1) * 10 + j) * NC];
        }
        float vcur[10];
        #pragma unroll
        for (int j = 0; j < 10; ++j) vcur[j] = (inh[i] && inw[j]) ? 0.0f : raw1[j];
        float rm[10];
        #pragma unroll
        for (int j = 0; j < 10; ++j) rm[j] = fmaxf(vprev[j], vcur[j]);

        float pr[9];
        #pragma unroll
        for (int j = 0; j < 9; ++j) pr[j] = fmaxf(rm[j], rm[j + 1]);

        // Direct per-lane store: 9 consecutive floats at dst + (i-1)*9.
        // 4B-aligned dwordx4 is fine on gfx950 (unaligned-access-mode).
        float* d = dst + (i - 1) * 9;
        *reinterpret_cast<f4v*>(d)     = f4v{pr[0], pr[1], pr[2], pr[3]};
        *reinterpret_cast<f4v*>(d + 4) = f4v{pr[4], pr[5], pr[6], pr[7]};
        d[8] = pr[8];

        #pragma unroll
        for (int j = 0; j < 10; ++j) vprev[j] = vcur[j];
        if (i < 9) {
            #pragma unroll
            for (int j = 0; j < 10; ++j) raw1[j] = rawn[j];
        }
    }
}

extern "C" void kernel_launch(void* const* d_in, const int* in_sizes, int n_in,
                              void* d_out, int out_size, void* d_ws, size_t ws_size,
                              hipStream_t stream) {
    const float* F    = (const float*)d_in[0];   // 4*256*64*64
    const float* rois = (const float*)d_in[1];   // 2048*5
    float*       out  = (float*)d_out;           // 2048*256*9*9
    float*       G    = (float*)d_ws;            // 4*100*256 floats = 409600 B

    rod_gather<<<dim3(400), dim3(256), 0, stream>>>(F, G);
    rod_main<<<dim3(NR * 4), dim3(64), 0, stream>>>(G, rois, out);
}

// Round 3
// 178.495 us; speedup vs baseline: 1.2519x; 1.2519x over previous
//
#include <hip/hip_runtime.h>

// RoDAlignMax: features [4,256,64,64] f32, rois [2048,5] -> out [2048,256,9,9] f32
// Grid samples are exactly (7i, 7j): bilinear degenerates to a gather.
// Kernel 1: gather G[b][p][c] (p = i*10+j, 100 points) = F[b,c,7i,7j]  (400 KB, L3-resident)
// Kernel 2: one wave per (roi, 32-channel chunk). Half-wave A: pooled rows 0-3
//           (input rows 0-5); half-wave B: pooled rows 4-8 (input rows 4-9).
//           All 60 loads issued up-front (single latency exposure). LDS [32][81]
//           mirrors the contiguous global chunk -> b128 reads + dwordx4 stores.
//           10.1 KB LDS -> ~15 blocks/CU (2.1x round-1 occupancy).

#define NB 4
#define NC 256
#define HW 64
#define NR 2048

__global__ __launch_bounds__(256) void rod_gather(const float* __restrict__ F,
                                                  float* __restrict__ G) {
    int idx = blockIdx.x * 256 + threadIdx.x;      // < 4*100*256 = 102400
    int c = idx & 255;
    int t = idx >> 8;                              // b*100 + p
    int p = t % 100;
    int b = t / 100;
    int i = p / 10, j = p - i * 10;
    // F[((b*256 + c)*64 + 7i)*64 + 7j]
    G[idx] = F[((b * NC + c) << 12) + i * 448 + j * 7];
}

__global__ __launch_bounds__(64, 2) void rod_main(const float* __restrict__ G,
                                                  const float* __restrict__ rois,
                                                  float* __restrict__ out) {
    // 32 channels x 81 outputs, layout identical to the global output slice.
    __shared__ __align__(16) float lds[32 * 81];   // 10368 B -> ~15 blocks/CU
    const int tid   = threadIdx.x;
    const int r     = blockIdx.x >> 3;
    const int oct   = blockIdx.x & 7;              // 32-channel chunk
    const int cl    = tid & 31;                    // channel within chunk
    const int c     = (oct << 5) + cl;
    const int rbase = (tid >> 5) << 2;             // 0 (half A) or 4 (half B)

    const float x1 = rois[r * 5 + 1] * 0.25f;
    const float y1 = rois[r * 5 + 2] * 0.25f;
    const float x2 = rois[r * 5 + 3] * 0.25f;
    const float y2 = rois[r * 5 + 4] * 0.25f;
    const int  b   = (int)rois[r * 5 + 0];

    bool inw[10];                                  // wave-uniform column masks
    #pragma unroll
    for (int j = 0; j < 10; ++j) {
        float s = 7.0f * (float)j;                 // exact grid coordinate
        inw[j] = (s >= x1) && (s <= x2);
    }
    bool inh[6];                                   // my 6 input rows: rbase..rbase+5
    #pragma unroll
    for (int k = 0; k < 6; ++k) {
        float s = 7.0f * (float)(rbase + k);
        inh[k] = (s >= y1) && (s <= y2);
    }

    // G[b][p][c]: per instruction, two dense 128 B segments (one per half-wave).
    const float* gb = G + (size_t)b * 100 * NC + c;

    // Issue all 60 loads up-front: one latency exposure instead of ten.
    float raw[6][10];
    #pragma unroll
    for (int k = 0; k < 6; ++k)
        #pragma unroll
        for (int j = 0; j < 10; ++j)
            raw[k][j] = gb[((rbase + k) * 10 + j) * NC];

    float m[6][10];                                // masked samples
    #pragma unroll
    for (int k = 0; k < 6; ++k)
        #pragma unroll
        for (int j = 0; j < 10; ++j)
            m[k][j] = (inh[k] && inw[j]) ? 0.0f : raw[k][j];

    float cm[5][10];                               // vertical max of row pairs
    #pragma unroll
    for (int k = 0; k < 5; ++k)
        #pragma unroll
        for (int j = 0; j < 10; ++j)
            cm[k][j] = fmaxf(m[k][j], m[k + 1][j]);

    // Pooled row t = rbase + k; half A writes k=0..3, half B writes k=0..4.
    #pragma unroll
    for (int k = 0; k < 5; ++k) {
        if (k == 4 && rbase == 0) continue;        // row 4 owned by half B
        #pragma unroll
        for (int j = 0; j < 9; ++j)
            lds[cl * 81 + (rbase + k) * 9 + j] = fmaxf(cm[k][j], cm[k][j + 1]);
    }
    __syncthreads();                               // single wave: just a waitcnt drain

    // LDS mirrors out[r][oct*32..][81] exactly: pure vector copy, no index math.
    const float4* lds4 = reinterpret_cast<const float4*>(lds);
    float4* dst4 = reinterpret_cast<float4*>(out + (size_t)r * 20736 + oct * 2592);
    #pragma unroll
    for (int k = 0; k < 10; ++k)
        dst4[tid + (k << 6)] = lds4[tid + (k << 6)];
    if (tid < 8)                                   // 32*81/4 = 648 = 10*64 + 8
        dst4[tid + 640] = lds4[tid + 640];
}

extern "C" void kernel_launch(void* const* d_in, const int* in_sizes, int n_in,
                              void* d_out, int out_size, void* d_ws, size_t ws_size,
                              hipStream_t stream) {
    const float* F    = (const float*)d_in[0];   // 4*256*64*64
    const float* rois = (const float*)d_in[1];   // 2048*5
    float*       out  = (float*)d_out;           // 2048*256*9*9
    float*       G    = (float*)d_ws;            // 4*100*256 floats = 409600 B

    rod_gather<<<dim3(400), dim3(256), 0, stream>>>(F, G);
    rod_main<<<dim3(NR * 8), dim3(64), 0, stream>>>(G, rois, out);
}

// Round 4
// 178.167 us; speedup vs baseline: 1.2542x; 1.0018x over previous
//
#include <hip/hip_runtime.h>

// RoDAlignMax: features [4,256,64,64] f32, rois [2048,5] -> out [2048,256,9,9] f32
// Grid samples are exactly (7i, 7j): bilinear degenerates to a gather.
// Kernel 1: gather G[b][i][c][j] (j fastest!) = F[b,c,7i,7j]  (400 KB, L2/L3-resident)
// Kernel 2: one wave per (roi, 32-channel chunk). Half-wave A: pooled rows 0-3
//           (input rows 0-5); half-wave B: pooled rows 4-8 (input rows 4-9).
//           Row loads are dwordx4+dwordx4+dwordx2 (18 load instrs/lane vs 60 scalar);
//           LDS [32][81] mirrors the contiguous global chunk -> b128 + dwordx4 out.

#define NB 4
#define NC 256
#define HW 64
#define NR 2048

typedef float f4v __attribute__((ext_vector_type(4), aligned(4)));
typedef float f2v __attribute__((ext_vector_type(2), aligned(4)));

__global__ __launch_bounds__(256) void rod_gather(const float* __restrict__ F,
                                                  float* __restrict__ G) {
    int idx = blockIdx.x * 256 + threadIdx.x;      // < 4*10*256*10 = 102400
    int j = idx % 10;                              // sample column (fastest)
    int t = idx / 10;                              // (b*10 + i)*256 + c
    int c = t & 255;
    int s = t >> 8;                                // b*10 + i
    int i = s % 10;
    int b = s / 10;
    // F[((b*256 + c)*64 + 7i)*64 + 7j]
    G[idx] = F[((b * NC + c) << 12) + i * 448 + j * 7];
}

__global__ __launch_bounds__(64, 2) void rod_main(const float* __restrict__ G,
                                                  const float* __restrict__ rois,
                                                  float* __restrict__ out) {
    // 32 channels x 81 outputs, layout identical to the global output slice.
    __shared__ __align__(16) float lds[32 * 81];   // 10368 B -> ~15 blocks/CU
    const int tid   = threadIdx.x;
    const int r     = blockIdx.x >> 3;
    const int oct   = blockIdx.x & 7;              // 32-channel chunk
    const int cl    = tid & 31;                    // channel within chunk
    const int c     = (oct << 5) + cl;
    const int rbase = (tid >> 5) << 2;             // 0 (half A) or 4 (half B)

    const float x1 = rois[r * 5 + 1] * 0.25f;
    const float y1 = rois[r * 5 + 2] * 0.25f;
    const float x2 = rois[r * 5 + 3] * 0.25f;
    const float y2 = rois[r * 5 + 4] * 0.25f;
    const int  b   = (int)rois[r * 5 + 0];

    bool inw[10];                                  // wave-uniform column masks
    #pragma unroll
    for (int j = 0; j < 10; ++j) {
        float s = 7.0f * (float)j;                 // exact grid coordinate
        inw[j] = (s >= x1) && (s <= x2);
    }
    bool inh[6];                                   // my 6 input rows: rbase..rbase+5
    #pragma unroll
    for (int k = 0; k < 6; ++k) {
        float s = 7.0f * (float)(rbase + k);
        inh[k] = (s >= y1) && (s <= y2);
    }

    // Row base in G[b][i][c][j]: one address per row, imm offsets 0/16/32 for the
    // three vector loads. 18 load instructions total (vs 60 scalar in the old layout).
    const float* gb = G + ((size_t)(b * 10 + rbase) * NC + c) * 10;

    f4v a0[6]; f4v a1[6]; f2v a2[6];
    #pragma unroll
    for (int k = 0; k < 6; ++k) {
        const float* rp = gb + k * (NC * 10);
        a0[k] = *reinterpret_cast<const f4v*>(rp);
        a1[k] = *reinterpret_cast<const f4v*>(rp + 4);
        a2[k] = *reinterpret_cast<const f2v*>(rp + 8);
    }

    float m[6][10];                                // masked samples
    #pragma unroll
    for (int k = 0; k < 6; ++k) {
        const bool ih = inh[k];
        #pragma unroll
        for (int j = 0; j < 4; ++j) m[k][j]     = (ih && inw[j])     ? 0.0f : a0[k][j];
        #pragma unroll
        for (int j = 0; j < 4; ++j) m[k][4 + j] = (ih && inw[4 + j]) ? 0.0f : a1[k][j];
        #pragma unroll
        for (int j = 0; j < 2; ++j) m[k][8 + j] = (ih && inw[8 + j]) ? 0.0f : a2[k][j];
    }

    float cm[5][10];                               // vertical max of row pairs
    #pragma unroll
    for (int k = 0; k < 5; ++k)
        #pragma unroll
        for (int j = 0; j < 10; ++j)
            cm[k][j] = fmaxf(m[k][j], m[k + 1][j]);

    // Pooled row t = rbase + k; half A writes k=0..3, half B writes k=0..4.
    #pragma unroll
    for (int k = 0; k < 5; ++k) {
        if (k == 4 && rbase == 0) continue;        // row 4 owned by half B
        #pragma unroll
        for (int j = 0; j < 9; ++j)
            lds[cl * 81 + (rbase + k) * 9 + j] = fmaxf(cm[k][j], cm[k][j + 1]);
    }
    __syncthreads();                               // single wave: just a waitcnt drain

    // LDS mirrors out[r][oct*32..][81] exactly: pure vector copy, no index math.
    const float4* lds4 = reinterpret_cast<const float4*>(lds);
    float4* dst4 = reinterpret_cast<float4*>(out + (size_t)r * 20736 + oct * 2592);
    #pragma unroll
    for (int k = 0; k < 10; ++k)
        dst4[tid + (k << 6)] = lds4[tid + (k << 6)];
    if (tid < 8)                                   // 32*81/4 = 648 = 10*64 + 8
        dst4[tid + 640] = lds4[tid + 640];
}

extern "C" void kernel_launch(void* const* d_in, const int* in_sizes, int n_in,
                              void* d_out, int out_size, void* d_ws, size_t ws_size,
                              hipStream_t stream) {
    const float* F    = (const float*)d_in[0];   // 4*256*64*64
    const float* rois = (const float*)d_in[1];   // 2048*5
    float*       out  = (float*)d_out;           // 2048*256*9*9
    float*       G    = (float*)d_ws;            // 4*10*256*10 floats = 409600 B

    rod_gather<<<dim3(400), dim3(256), 0, stream>>>(F, G);
    rod_main<<<dim3(NR * 8), dim3(64), 0, stream>>>(G, rois, out);
}